// Round 1
// 1267.099 us; speedup vs baseline: 1.0175x; 1.0175x over previous
//
#include <hip/hip_runtime.h>

// ---------------------------------------------------------------------------
// SAM windowed-attention block, bf16-MFMA implementation.
// B=8 H=W=64 DIM=768 NH=12 HD=64 WS=14 N=196 PAD=6 -> 70x70, 5x5=25 windows,
// Bp=200 windows, 2400 (window,head) pairs. All GEMMs bf16 MFMA 16x16x32,
// fp32 accumulate. Softmax/LN/gelu in fp32.
// R1: gemm_bt staging via global_load_lds dwordx4 (linear LDS stride 32) +
//     bijective XCD-chunked block swizzle.
// ---------------------------------------------------------------------------

typedef __bf16 bf16x8 __attribute__((ext_vector_type(8)));
typedef float f32x4 __attribute__((ext_vector_type(4)));
typedef unsigned int u32x4 __attribute__((ext_vector_type(4)));

__device__ __forceinline__ unsigned short f2bf(float f) {
  unsigned int u = __builtin_bit_cast(unsigned int, f);
  u += 0x7FFFu + ((u >> 16) & 1u);
  return (unsigned short)(u >> 16);
}

__device__ __forceinline__ bf16x8 ld8(const unsigned short* p) {
  return __builtin_bit_cast(bf16x8, *(const u32x4*)p);
}

// async global->LDS, 16B per lane. LDS dest must be wave-uniform base + lane*16.
__device__ __forceinline__ void gload_lds16(const unsigned short* g,
                                            unsigned short* l) {
  __builtin_amdgcn_global_load_lds(
      (const __attribute__((address_space(1))) unsigned int*)g,
      (__attribute__((address_space(3))) unsigned int*)l, 16, 0, 0);
}

// ---------------------------------------------------------------------------
// Weight transpose fp32[K][N] -> bf16[N][K]  (all dims multiples of 32)
// ---------------------------------------------------------------------------
__global__ void transpose_w(const float* __restrict__ in,
                            unsigned short* __restrict__ out, int K, int N) {
  __shared__ float t[32][33];
  int n = blockIdx.x * 32 + threadIdx.x;
  int kb = blockIdx.y * 32;
#pragma unroll
  for (int i = 0; i < 4; i++) {
    int k = kb + threadIdx.y + i * 8;
    t[threadIdx.y + i * 8][threadIdx.x] = in[(size_t)k * N + n];
  }
  __syncthreads();
  int k2 = kb + threadIdx.x;
#pragma unroll
  for (int i = 0; i < 4; i++) {
    int n2 = blockIdx.x * 32 + threadIdx.y + i * 8;
    out[(size_t)n2 * K + k2] = f2bf(t[threadIdx.x][threadIdx.y + i * 8]);
  }
}

// ---------------------------------------------------------------------------
// Rel-pos tables: Sh[i*14+j] = sum_c rel_h[(i-j+13)*64+c]; same for Sw.
// out layout: [0..195]=Sh, [196..391]=Sw
// ---------------------------------------------------------------------------
__global__ void shsw_kernel(const float* __restrict__ rh,
                            const float* __restrict__ rw,
                            float* __restrict__ o) {
  int t = threadIdx.x;
  if (t < 196) {
    int i = t / 14, j = t % 14, d = i - j + 13;
    float sh = 0.f, sw = 0.f;
    for (int c = 0; c < 64; c++) {
      sh += rh[d * 64 + c];
      sw += rw[d * 64 + c];
    }
    o[t] = sh;
    o[196 + t] = sw;
  }
}

// ---------------------------------------------------------------------------
// LayerNorm over 768. windowed=1: write to window-partitioned layout
// [win*196+t][768]; windowed=0: write [row][768]. Output bf16.
// ---------------------------------------------------------------------------
__global__ __launch_bounds__(256) void ln_kernel(
    const float* __restrict__ xin, const float* __restrict__ w,
    const float* __restrict__ b, unsigned short* __restrict__ out,
    int windowed) {
  __shared__ float red[8];
  __shared__ float ms[2];
  const int tid = threadIdx.x;
  const int blk = blockIdx.x;
  const float* xr = xin + (size_t)blk * 768;
  float v0 = xr[tid], v1 = xr[tid + 256], v2 = xr[tid + 512];
  float s = v0 + v1 + v2;
  float q = v0 * v0 + v1 * v1 + v2 * v2;
#pragma unroll
  for (int off = 32; off > 0; off >>= 1) {
    s += __shfl_down(s, off, 64);
    q += __shfl_down(q, off, 64);
  }
  const int wv = tid >> 6, lane = tid & 63;
  if (lane == 0) { red[wv] = s; red[4 + wv] = q; }
  __syncthreads();
  if (tid == 0) {
    float st = red[0] + red[1] + red[2] + red[3];
    float qt = red[4] + red[5] + red[6] + red[7];
    float mu = st * (1.0f / 768.0f);
    float var = qt * (1.0f / 768.0f) - mu * mu;
    ms[0] = mu;
    ms[1] = rsqrtf(var + 1e-5f);
  }
  __syncthreads();
  float mu = ms[0], sc = ms[1];
  unsigned short* dst;
  if (windowed) {
    int bb = blk >> 12, rem = blk & 4095, h = rem >> 6, ww = rem & 63;
    int win = (bb * 5 + h / 14) * 5 + ww / 14;
    int t = (h % 14) * 14 + (ww % 14);
    dst = out + ((size_t)win * 196 + t) * 768;
  } else {
    dst = out + (size_t)blk * 768;
  }
  dst[tid] = f2bf((v0 - mu) * sc * w[tid] + b[tid]);
  dst[tid + 256] = f2bf((v1 - mu) * sc * w[tid + 256] + b[tid + 256]);
  dst[tid + 512] = f2bf((v2 - mu) * sc * w[tid + 512] + b[tid + 512]);
}

// ---------------------------------------------------------------------------
// bf16 GEMM: C[M][N] = A[M][K] @ Bt[N][K]^T (+ epilogue)
// 128x128 block tile, BK=32, 4 waves in 2x2, each wave 64x64 (4x4 MFMA tiles).
// Staging: global_load_lds dwordx4 (DMA, no VGPR round-trip). LDS linear
// stride 32 (required: DMA dest is wave-base + lane*16B; no padding allowed).
// XCD-chunked bijective block swizzle: blocks sharing an A-panel land on the
// same XCD's L2 (grid.x is small: 6..24), cutting A re-fetch from HBM.
// EPI: 0=+bias->bf16 (qkv), 1=+bias+resid, window-unpartition ->fp32 d_out
//      2=+bias,gelu->bf16 (mlp1), 3=+bias, d_out += (mlp2)
// ---------------------------------------------------------------------------
template <int EPI>
__global__ __launch_bounds__(256, 2) void gemm_bt(
    const unsigned short* __restrict__ A, const unsigned short* __restrict__ Bt,
    const float* __restrict__ bias, int M, int N, int K,
    unsigned short* __restrict__ obf, float* __restrict__ of,
    const float* __restrict__ resid) {
  __shared__ __align__(16) unsigned short As[128 * 32];
  __shared__ __align__(16) unsigned short Bs[128 * 32];
  const int tid = threadIdx.x;
  const int lane = tid & 63, wv = tid >> 6;
  const int ln15 = lane & 15, quad = lane >> 4;
  const int wm = wv & 1, wn = wv >> 1;

  // bijective XCD-chunked swizzle (8 XCDs): original linear id b dispatches to
  // XCD b%8; remap so each XCD computes a contiguous chunk of tiles.
  int bid = blockIdx.y * gridDim.x + blockIdx.x;
  {
    const int nwg = gridDim.x * gridDim.y;
    const int q = nwg >> 3, r = nwg & 7;
    const int xcd = bid & 7, lo = bid >> 3;
    bid = (xcd < r ? xcd * (q + 1) : r * (q + 1) + (xcd - r) * q) + lo;
  }
  const int m0 = (bid / gridDim.x) * 128, n0 = (bid % gridDim.x) * 128;

  // thread t stages 16B: row t>>2 (then +64), cols (t&3)*8.. of the BK=32 slab.
  // LDS index = (t>>2)*32 + (t&3)*8 = t*8 -> contiguous, wave-base + lane*16B.
  const int ra0 = tid >> 2, ka0 = (tid & 3) * 8;
  const unsigned short* pA0 = A + (size_t)min(m0 + ra0, M - 1) * K + ka0;
  const unsigned short* pA1 = A + (size_t)min(m0 + ra0 + 64, M - 1) * K + ka0;
  const unsigned short* pB0 = Bt + (size_t)(n0 + ra0) * K + ka0;
  const unsigned short* pB1 = Bt + (size_t)(n0 + ra0 + 64) * K + ka0;
  unsigned short* lA0 = As + tid * 8;
  unsigned short* lA1 = As + 2048 + tid * 8;
  unsigned short* lB0 = Bs + tid * 8;
  unsigned short* lB1 = Bs + 2048 + tid * 8;

  const f32x4 fz = {0.f, 0.f, 0.f, 0.f};
  f32x4 acc[4][4];
#pragma unroll
  for (int i = 0; i < 4; i++)
#pragma unroll
    for (int j = 0; j < 4; j++) acc[i][j] = fz;

  for (int kt = 0; kt < K; kt += 32) {
    __syncthreads();  // all waves done reading previous slab
    gload_lds16(pA0 + kt, lA0);
    gload_lds16(pA1 + kt, lA1);
    gload_lds16(pB0 + kt, lB0);
    gload_lds16(pB1 + kt, lB1);
    __syncthreads();  // drains vmcnt(0): slab visible in LDS
    bf16x8 af[4], bv[4];
#pragma unroll
    for (int t = 0; t < 4; t++) {
      af[t] = ld8(As + (wm * 64 + t * 16 + ln15) * 32 + quad * 8);
      bv[t] = ld8(Bs + (wn * 64 + t * 16 + ln15) * 32 + quad * 8);
    }
#pragma unroll
    for (int i = 0; i < 4; i++)
#pragma unroll
      for (int j = 0; j < 4; j++)
        acc[i][j] =
            __builtin_amdgcn_mfma_f32_16x16x32_bf16(af[i], bv[j], acc[i][j], 0, 0, 0);
  }

  // Epilogue. C/D layout: col = lane&15, row = quad*4 + reg (verified m89/m91).
#pragma unroll
  for (int i = 0; i < 4; i++) {
#pragma unroll
    for (int j = 0; j < 4; j++) {
      const int col = n0 + wn * 64 + j * 16 + ln15;
      const float bc = bias[col];
#pragma unroll
      for (int g = 0; g < 4; g++) {
        const int row = m0 + wm * 64 + i * 16 + quad * 4 + g;
        if (row >= M) continue;
        float v = acc[i][j][g] + bc;
        if constexpr (EPI == 0) {
          obf[(size_t)row * N + col] = f2bf(v);
        } else if constexpr (EPI == 2) {
          float gl = 0.5f * v * (1.0f + erff(v * 0.70710678118f));
          obf[(size_t)row * N + col] = f2bf(gl);
        } else if constexpr (EPI == 1) {
          // row -> (b,h,w) via window unpartition; drop padded positions
          int win = row / 196, t = row - win * 196;
          int b = win / 25, wg = win - b * 25;
          int wr = wg / 5, wc = wg - wr * 5;
          int h = wr * 14 + t / 14;
          int w = wc * 14 + (t % 14);
          if (h < 64 && w < 64) {
            size_t oi = (((size_t)(b * 64 + h)) * 64 + w) * 768 + col;
            of[oi] = v + resid[oi];
          }
        } else {  // EPI == 3
          size_t oi = (size_t)row * N + col;
          of[oi] += v;
        }
      }
    }
  }
}

// ---------------------------------------------------------------------------
// Fused windowed attention: one block per (window, head). 2400 blocks.
// qkv: bf16 [200*196][2304]; q cols h*64.., k cols 768+h*64.., v 1536+h*64..
// S = (Q Kt)*0.125 + Sh[qr,kr] + Sw[qc,kc]; softmax; O = P V.
// Q/K fragments read directly from global (L1-resident); V transposed in LDS;
// P strip round-trips LDS per wave (C-layout -> A-layout).
// ---------------------------------------------------------------------------
__global__ __launch_bounds__(256, 2) void attn_kernel(
    const unsigned short* __restrict__ qkv, const int* __restrict__ q_idx,
    const int* __restrict__ k_idx, const float* __restrict__ shsw,
    unsigned short* __restrict__ attnout) {
  __shared__ __align__(16) unsigned short Vt[64][232];   // [channel][key] pad->2-way banks
  __shared__ __align__(16) unsigned short Pst[4][16 * 232];  // per-wave P strip
  __shared__ float Shs[196], Sws[196];
  __shared__ short qr14a[208], qc14a[208], kra[208], kca[208];

  const int tid = threadIdx.x;
  const int blk = blockIdx.x;
  const int win = blk / 12, head = blk % 12;
  const int lane = tid & 63, wv = tid >> 6;
  const int ln15 = lane & 15, quad = lane >> 4;
  const unsigned short* qg = qkv + (size_t)win * 196 * 2304;

  // zero Vt & Pst (covers key/col padding 196..223 and strip cols 208..223)
  {
    unsigned int* vz = (unsigned int*)&Vt[0][0];
    for (int i = tid; i < 64 * 232 / 2; i += 256) vz[i] = 0u;
    unsigned int* pz = (unsigned int*)&Pst[0][0];
    for (int i = tid; i < 4 * 16 * 232 / 2; i += 256) pz[i] = 0u;
  }
  // V -> Vt transposed
  for (int i = tid; i < 196 * 64; i += 256) {
    int r = i >> 6, c = i & 63;
    Vt[c][r] = qg[(size_t)r * 2304 + 1536 + head * 64 + c];
  }
  // bias tables + index arrays
  for (int i = tid; i < 208; i += 256) {
    if (i < 196) {
      Shs[i] = shsw[i];
      Sws[i] = shsw[196 + i];
    }
    int q = (i < 196) ? q_idx[(size_t)blk * 196 + i] : 0;
    int k = (i < 196) ? k_idx[(size_t)blk * 196 + i] : 0;
    qr14a[i] = (short)((q / 14) * 14);
    qc14a[i] = (short)((q % 14) * 14);
    kra[i] = (short)(k / 14);
    kca[i] = (short)(k % 14);
  }
  __syncthreads();

  const f32x4 fz = {0.f, 0.f, 0.f, 0.f};
  unsigned short* strip = &Pst[wv][0];

  for (int mt = wv; mt < 13; mt += 4) {
    // ---- Q fragments (A-layout: m=lane&15, k=quad*8+j) from global ----
    int qrow = mt * 16 + ln15;
    int qrc = (qrow < 196) ? qrow : 0;
    const unsigned short* qrp = qg + (size_t)qrc * 2304 + head * 64 + quad * 8;
    bf16x8 aq0 = ld8(qrp);
    bf16x8 aq1 = ld8(qrp + 32);

    // ---- S = Q K^T over 13 col tiles ----
    f32x4 sacc[13];
#pragma unroll
    for (int nt = 0; nt < 13; nt++) {
      sacc[nt] = fz;
      int krow = nt * 16 + ln15;
      if (krow > 195) krow = 0;
      const unsigned short* krp =
          qg + (size_t)krow * 2304 + 768 + head * 64 + quad * 8;
      bf16x8 bk0 = ld8(krp);
      bf16x8 bk1 = ld8(krp + 32);
      sacc[nt] = __builtin_amdgcn_mfma_f32_16x16x32_bf16(aq0, bk0, sacc[nt], 0, 0, 0);
      sacc[nt] = __builtin_amdgcn_mfma_f32_16x16x32_bf16(aq1, bk1, sacc[nt], 0, 0, 0);
    }

    // ---- softmax (rows = quad*4+g of this mt tile) ----
    const int r0 = mt * 16 + quad * 4;
    int qi[4], qci[4];
#pragma unroll
    for (int g = 0; g < 4; g++) {
      qi[g] = qr14a[r0 + g];
      qci[g] = qc14a[r0 + g];
    }
    float rmax[4] = {-1e30f, -1e30f, -1e30f, -1e30f};
#pragma unroll
    for (int nt = 0; nt < 13; nt++) {
      int col = nt * 16 + ln15;
      int kr_ = kra[col], kc_ = kca[col];
#pragma unroll
      for (int g = 0; g < 4; g++) {
        float v = sacc[nt][g] * 0.125f + Shs[qi[g] + kr_] + Sws[qci[g] + kc_];
        if (col >= 196) v = -1e30f;
        sacc[nt][g] = v;
        rmax[g] = fmaxf(rmax[g], v);
      }
    }
#pragma unroll
    for (int off = 1; off < 16; off <<= 1)
#pragma unroll
      for (int g = 0; g < 4; g++)
        rmax[g] = fmaxf(rmax[g], __shfl_xor(rmax[g], off, 16));
    float rsum[4] = {0.f, 0.f, 0.f, 0.f};
#pragma unroll
    for (int nt = 0; nt < 13; nt++) {
      int col = nt * 16 + ln15;
#pragma unroll
      for (int g = 0; g < 4; g++) {
        float p = (col >= 196) ? 0.f : __expf(sacc[nt][g] - rmax[g]);
        sacc[nt][g] = p;
        rsum[g] += p;
      }
    }
#pragma unroll
    for (int off = 1; off < 16; off <<= 1)
#pragma unroll
      for (int g = 0; g < 4; g++) rsum[g] += __shfl_xor(rsum[g], off, 16);
    float rinv[4];
#pragma unroll
    for (int g = 0; g < 4; g++) rinv[g] = 1.0f / rsum[g];

    // ---- write P strip (row-major [16][232] bf16, A-layout source for PV) ----
#pragma unroll
    for (int nt = 0; nt < 13; nt++) {
      int col = nt * 16 + ln15;
#pragma unroll
      for (int g = 0; g < 4; g++)
        strip[(quad * 4 + g) * 232 + col] = f2bf(sacc[nt][g] * rinv[g]);
    }

    // ---- O = P V  (K padded to 224; strip/Vt zeros beyond 196) ----
    f32x4 oacc[4];
#pragma unroll
    for (int c4 = 0; c4 < 4; c4++) oacc[c4] = fz;
#pragma unroll
    for (int ks = 0; ks < 7; ks++) {
      bf16x8 ap = ld8(strip + ln15 * 232 + ks * 32 + quad * 8);
#pragma unroll
      for (int c4 = 0; c4 < 4; c4++) {
        bf16x8 bvv = ld8(&Vt[c4 * 16 + ln15][ks * 32 + quad * 8]);
        oacc[c4] = __builtin_amdgcn_mfma_f32_16x16x32_bf16(ap, bvv, oacc[c4], 0, 0, 0);
      }
    }
    // ---- store (C-layout: col=lane&15 channel, row=quad*4+g token) ----
#pragma unroll
    for (int c4 = 0; c4 < 4; c4++)
#pragma unroll
      for (int g = 0; g < 4; g++) {
        int row = r0 + g;
        if (row < 196)
          attnout[((size_t)win * 196 + row) * 768 + head * 64 + c4 * 16 + ln15] =
              f2bf(oacc[c4][g]);
      }
  }
}

// ---------------------------------------------------------------------------
// Launch. Workspace layout (bytes):
//   [0, 60211200)              region A: xw bf16 [39200][768] -> attnout -> ln2
//   [60211200, 261537792)      region B: qkv bf16 [39200][2304] -> mlp1 [32768][3072]
//   [261537792, ...)           transposed weights bf16 + ShSw tables (~14.2 MB)
// Peak ws use ~276 MB.
// ---------------------------------------------------------------------------
extern "C" void kernel_launch(void* const* d_in, const int* in_sizes, int n_in,
                              void* d_out, int out_size, void* d_ws,
                              size_t ws_size, hipStream_t stream) {
  const float* x = (const float*)d_in[0];
  const int* q_idx = (const int*)d_in[1];
  const int* k_idx = (const int*)d_in[2];
  const float* ln1w = (const float*)d_in[3];
  const float* ln1b = (const float*)d_in[4];
  const float* ln2w = (const float*)d_in[5];
  const float* ln2b = (const float*)d_in[6];
  const float* qkvw = (const float*)d_in[7];
  const float* qkvb = (const float*)d_in[8];
  const float* projw = (const float*)d_in[9];
  const float* projb = (const float*)d_in[10];
  const float* relh = (const float*)d_in[11];
  const float* relw = (const float*)d_in[12];
  const float* w1 = (const float*)d_in[13];
  const float* b1 = (const float*)d_in[14];
  const float* w2 = (const float*)d_in[15];
  const float* b2 = (const float*)d_in[16];
  float* out = (float*)d_out;

  char* ws = (char*)d_ws;
  unsigned short* xw = (unsigned short*)ws;  // region A
  const size_t offA = 60211200;              // 39200*768*2
  unsigned short* qkv = (unsigned short*)(ws + offA);  // region B
  const size_t offB = offA + 201326592;      // max(qkv, mlp1)
  unsigned short* qkvwt = (unsigned short*)(ws + offB);
  unsigned short* projwt = qkvwt + 2304 * 768;
  unsigned short* w1t = projwt + 768 * 768;
  unsigned short* w2t = w1t + 3072 * 768;
  float* shsw = (float*)(w2t + 768 * 3072);

  unsigned short* attnout = xw;  // region A reuse (xw dead after qkv GEMM)
  unsigned short* ln2buf = xw;   // region A reuse (attnout dead after proj)
  unsigned short* mlp1 = qkv;    // region B reuse (qkv dead after attention)

  // zero xw so spatially-padded window tokens are zero feature vectors
  hipMemsetAsync(xw, 0, (size_t)39200 * 768 * 2, stream);

  dim3 tb(32, 8);
  transpose_w<<<dim3(2304 / 32, 768 / 32), tb, 0, stream>>>(qkvw, qkvwt, 768, 2304);
  transpose_w<<<dim3(768 / 32, 768 / 32), tb, 0, stream>>>(projw, projwt, 768, 768);
  transpose_w<<<dim3(3072 / 32, 768 / 32), tb, 0, stream>>>(w1, w1t, 768, 3072);
  transpose_w<<<dim3(768 / 32, 3072 / 32), tb, 0, stream>>>(w2, w2t, 3072, 768);
  shsw_kernel<<<1, 256, 0, stream>>>(relh, relw, shsw);

  // LN1 + window partition -> bf16
  ln_kernel<<<32768, 256, 0, stream>>>(x, ln1w, ln1b, xw, 1);

  // qkv = xw @ qkv_w + b   [39200,768]x[768,2304]
  gemm_bt<0><<<dim3(18, 307), 256, 0, stream>>>(xw, qkvwt, qkvb, 39200, 2304,
                                                768, qkv, nullptr, nullptr);
  // fused windowed attention
  attn_kernel<<<2400, 256, 0, stream>>>(qkv, q_idx, k_idx, shsw, attnout);

  // proj + residual + unpartition -> d_out (fp32 x_mid)
  gemm_bt<1><<<dim3(6, 307), 256, 0, stream>>>(attnout, projwt, projb, 39200,
                                               768, 768, nullptr, out, x);
  // LN2 -> bf16
  ln_kernel<<<32768, 256, 0, stream>>>(out, ln2w, ln2b, ln2buf, 0);

  // mlp1 = gelu(ln2 @ w1 + b1)   [32768,768]x[768,3072]
  gemm_bt<2><<<dim3(24, 256), 256, 0, stream>>>(ln2buf, w1t, b1, 32768, 3072,
                                                768, mlp1, nullptr, nullptr);
  // d_out += mlp1 @ w2 + b2      [32768,3072]x[3072,768]
  gemm_bt<3><<<dim3(6, 256), 256, 0, stream>>>(mlp1, w2t, b2, 32768, 768, 3072,
                                               nullptr, out, nullptr);
  (void)in_sizes; (void)n_in; (void)out_size; (void)ws_size;
}